// Round 1
// baseline (496.160 us; speedup 1.0000x reference)
//
#include <hip/hip_runtime.h>

#define NQ      14
#define NSTATE  16384   // 2^14
#define BLOCK   256
#define K_ITERS (NSTATE / 4 / BLOCK)  // 16

// One block per batch row. Thread t handles float4 chunks n4 = k*256 + t,
// i.e. elements n = 4*n4 + i.  Bit structure of n:
//   bits 0..1  = i        (inside float4)   -> qubits 13,12 : compile-time +/- combos
//   bits 2..9  = t        (thread index)    -> qubits 11..4 : per-thread fixed sign on S
//   bits 10..13= k        (unrolled loop)   -> qubits 3..0  : compile-time signed accs
__global__ __launch_bounds__(BLOCK) void meas_kernel(const float* __restrict__ sr,
                                                     const float* __restrict__ si,
                                                     float* __restrict__ out) {
    const int b = blockIdx.x;
    const int t = threadIdx.x;
    const float4* sr4 = (const float4*)(sr + (size_t)b * NSTATE);
    const float4* si4 = (const float4*)(si + (size_t)b * NSTATE);

    float acc13 = 0.f, acc12 = 0.f, S = 0.f;
    float acc0 = 0.f, acc1 = 0.f, acc2 = 0.f, acc3 = 0.f;

#pragma unroll
    for (int k = 0; k < K_ITERS; ++k) {
        const int n4 = k * BLOCK + t;
        const float4 a = sr4[n4];
        const float4 c = si4[n4];
        const float p0 = a.x * a.x + c.x * c.x;
        const float p1 = a.y * a.y + c.y * c.y;
        const float p2 = a.z * a.z + c.z * c.z;
        const float p3 = a.w * a.w + c.w * c.w;

        const float s02 = p0 + p2, s13 = p1 + p3;
        const float sum = s02 + s13;
        acc13 += s02 - s13;               // bit0 of n: + - + -
        acc12 += (p0 + p1) - (p2 + p3);   // bit1 of n: + + - -
        S     += sum;
        // qubit q in {0..3}: sign = (-1)^{bit (3-q) of k} -- compile-time after unroll
        acc0 += (k & 8) ? -sum : sum;
        acc1 += (k & 4) ? -sum : sum;
        acc2 += (k & 2) ? -sum : sum;
        acc3 += (k & 1) ? -sum : sum;
    }

    // Per-thread contribution for every qubit; all become PLAIN sums over the block.
    float v[NQ];
    v[0] = acc0; v[1] = acc1; v[2] = acc2; v[3] = acc3;
#pragma unroll
    for (int q = 4; q <= 11; ++q) {
        // qubit q: sign = (-1)^{bit (11-q) of t}
        v[q] = ((t >> (11 - q)) & 1) ? -S : S;
    }
    v[12] = acc12; v[13] = acc13;

    // Wave(64)-level shuffle reduction of all 14 values.
#pragma unroll
    for (int q = 0; q < NQ; ++q) {
        float x = v[q];
#pragma unroll
        for (int off = 32; off > 0; off >>= 1)
            x += __shfl_down(x, off, 64);
        v[q] = x;
    }

    __shared__ float red[BLOCK / 64][NQ];
    const int wave = t >> 6;
    const int lane = t & 63;
    if (lane == 0) {
#pragma unroll
        for (int q = 0; q < NQ; ++q) red[wave][q] = v[q];
    }
    __syncthreads();
    if (t < NQ) {
        out[(size_t)b * NQ + t] = red[0][t] + red[1][t] + red[2][t] + red[3][t];
    }
}

extern "C" void kernel_launch(void* const* d_in, const int* in_sizes, int n_in,
                              void* d_out, int out_size, void* d_ws, size_t ws_size,
                              hipStream_t stream) {
    const float* sr = (const float*)d_in[0];
    const float* si = (const float*)d_in[1];
    float* out = (float*)d_out;
    const int batch = in_sizes[0] / NSTATE;  // 4096
    meas_kernel<<<dim3(batch), dim3(BLOCK), 0, stream>>>(sr, si, out);
}